// Round 13
// baseline (214.464 us; speedup 1.0000x reference)
//
#include <hip/hip_runtime.h>

// StickyRNN: B=2048, T=1024, VOCAB=65, EMBED=6, HIDDEN=7
#define TV 65
#define NB 2048
#define NT 1024
#define NTOK 2097152u

typedef float f32x4 __attribute__((ext_vector_type(4)));

// workspace layout (in floats)
#define OFF_SP 0         // SP[cur*65+prev] = float2(Stc, Src)            (2*4225)
#define OFF_LP 8450      // LP[v*65+u]      = float2(Ltc, Lrc-Ltc)        (2*4225)
#define OFF_S0 16900     // S0[v] = dot(embed[v], hidden_init[0:6])       (65)
#define OFF_R  17792     // r[b*T+t] reset gate per step                  (2M), 64B-aligned

// Fused table build: one block. LP now stores (Ltc, D=Lrc-Ltc) so the
// projection blend is a single FMA: out = Ltc + r*D.
__global__ __launch_bounds__(256) void k_build(
    const float* __restrict__ embed, const float* __restrict__ ct,
    const float* __restrict__ rt, const float* __restrict__ hinit,
    const float* __restrict__ outw, float* __restrict__ ws) {
  __shared__ float tc_s[TV][6];
  __shared__ float rc_s[TV][6];
  int v = threadIdx.x;
  if (v < TV) {
    float e[6];
#pragma unroll
    for (int k = 0; k < 6; k++) e[k] = embed[v * 6 + k];
#pragma unroll
    for (int j = 0; j < 6; j++) {
      float stc = 0.f, src = 0.f;
#pragma unroll
      for (int k = 0; k < 6; k++) {
        stc += e[k] * ct[k * 6 + j];
        src += e[k] * rt[k * 6 + j];
      }
      tc_s[v][j] = stc;
      rc_s[v][j] = src;
    }
    float s0 = 0.f;
#pragma unroll
    for (int k = 0; k < 6; k++) s0 += e[k] * hinit[k];
    ws[OFF_S0 + v] = s0;
  }
  __syncthreads();
  for (int idx = threadIdx.x; idx < 2 * 4225; idx += 256) {
    int tbl = idx / 4225;
    int e2 = idx - tbl * 4225;
    int a = e2 / 65;
    int b = e2 - a * 65;
    if (tbl == 0) {
      float stc = 0.f, src = 0.f;
#pragma unroll
      for (int k = 0; k < 6; k++) {
        stc += embed[a * 6 + k] * tc_s[b][k];
        src += embed[a * 6 + k] * rc_s[b][k];
      }
      ((float2*)(ws + OFF_SP))[e2] = make_float2(stc, src);
    } else {
      float ltc = 0.f, lrc = 0.f;
#pragma unroll
      for (int k = 0; k < 6; k++) {
        ltc += tc_s[a][k] * outw[k * 65 + b];
        lrc += rc_s[a][k] * outw[k * 65 + b];
      }
      ((float2*)(ws + OFF_LP))[e2] = make_float2(ltc, lrc - ltc);
    }
  }
}

// Speculative chunk-parallel recurrence (bitwise-verified R2 vs R3; verbatim R8).
__global__ __launch_bounds__(256) void k_rnn_spec(
    const int* __restrict__ x, float* __restrict__ ws,
    const float* __restrict__ thr, const float* __restrict__ temp,
    const float* __restrict__ hinit) {
  __shared__ float2 sSP[4225];
  const float2* __restrict__ gSP = (const float2*)(ws + OFF_SP);
  for (int i = threadIdx.x; i < 4225; i += 256) sSP[i] = gSP[i];
  __syncthreads();

  const int tid = blockIdx.x * 256 + threadIdx.x;  // 0..65535
  const int c = tid >> 11;                         // chunk 0..31 (block-uniform)
  const int row = tid & 2047;
  const int t0 = c * 32;
  int s0 = t0 - 96;
  if (s0 < 0) s0 = 0;
  const bool exact = (s0 == 0);
  const int NG = (t0 + 32 - s0) >> 2;  // 8/16/24/32 groups of 4 steps

  const float t0v = thr[0];
  const float thr2 = t0v * t0v;
  const float invtemp = 1.0f / temp[0];
  const int* xp = x + row * NT;
  float* rbase = ws + OFF_R + row * NT;

  int4 xa = *(const int4*)(xp + s0);
  int4 xb = *(const int4*)(xp + s0 + 4);
  int4 xc = *(const int4*)(xp + s0 + 8);
  int4 xd = *(const int4*)(xp + s0 + 12);

  float pa, r_prev, omr_prev;
  float2 sp0;
  if (exact) {
    float s0v = ws[OFF_S0 + xa.x];
    sp0 = make_float2(s0v, s0v);  // 0.5*s+0.5*s == s exactly
    pa = hinit[6];
    r_prev = 0.5f;
    omr_prev = 0.5f;
  } else {
    int vm1 = xp[s0 - 1];
    sp0 = sSP[xa.x * 65 + vm1];
    pa = 0.0f;
    r_prev = 1.0f;
    omr_prev = 0.0f;
  }
  float2 sp1 = sSP[xa.y * 65 + xa.x];
  float2 sp2 = sSP[xa.z * 65 + xa.y];
  float2 sp3 = sSP[xa.w * 65 + xa.z];

#define STEP(SP, ROUT)                               \
  {                                                  \
    float sim = r_prev * (SP).y + omr_prev * (SP).x; \
    float prod = (1.0f + pa) * sim;                  \
    float aa = fmaxf(prod, 0.0f);                    \
    float add = aa - pa;                             \
    float na = pa + add;                             \
    float p = __expf((thr2 - na) * invtemp);         \
    float r = __builtin_amdgcn_rcpf(1.0f + p);       \
    float omr = 1.0f - r;                            \
    pa = omr * na;                                   \
    r_prev = r;                                      \
    omr_prev = omr;                                  \
    ROUT = r;                                        \
  }

  for (int g = 0; g < NG; ++g) {
    int offn = s0 + 4 * (g + 4);
    if (offn > NT - 4) offn = s0;
    int4 xe = *(const int4*)(xp + offn);
    float2 n0 = sSP[xb.x * 65 + xa.w];
    float2 n1 = sSP[xb.y * 65 + xb.x];
    float2 n2 = sSP[xb.z * 65 + xb.y];
    float2 n3 = sSP[xb.w * 65 + xb.z];

    float4 rq;
    STEP(sp0, rq.x);
    STEP(sp1, rq.y);
    STEP(sp2, rq.z);
    STEP(sp3, rq.w);
    int st = s0 + 4 * g;
    if (st >= t0) *(float4*)(rbase + st) = rq;  // block-uniform branch

    sp0 = n0; sp1 = n1; sp2 = n2; sp3 = n3;
    xa = xb; xb = xc; xc = xd; xd = xe;
  }
#undef STEP
}

// Projection, 16 consecutive floats per thread per iteration.
// 2080 blocks x 64KB-float windows = exact cover of 136,314,880 floats.
// A 16-float run crosses at most ONE token boundary -> token/r lookups
// amortized 4x vs the f4 version; 16 ds_read_b64 batch under one waitcnt;
// blend = 1 FMA via (Ltc, D). Incremental (n,v): stride 4096 == 1 (mod 65).
// x/r staged in LDS -> zero global reads in hot loop -> cached stores.
__global__ __launch_bounds__(256) void k_proj(
    const int* __restrict__ x, const float* __restrict__ ws,
    float* __restrict__ out) {
  __shared__ float2 sLP[4225];           // (Ltc, D)
  __shared__ float r_s[1016];
  __shared__ unsigned char x_s[1016];
  const unsigned b = blockIdx.x, t = threadIdx.x;
  const unsigned F0 = b * 65536u;        // first float of this block's window
  const unsigned n0 = F0 / 65u;          // first token touched

  const float2* __restrict__ gLP = (const float2*)(ws + OFF_LP);
  for (unsigned i = t; i < 4225u; i += 256u) sLP[i] = gLP[i];
  for (unsigned i = t; i < 1016u; i += 256u) {
    unsigned n = n0 + i;
    if (n > NTOK - 1u) n = NTOK - 1u;    // clamp (tail tokens unused)
    x_s[i] = (unsigned char)x[n];
    r_s[i] = ws[OFF_R + n];
  }
  __syncthreads();

  unsigned F = F0 + t * 16u;
  unsigned n = F / 65u;
  unsigned v = F - n * 65u;              // 0..64
  unsigned nl = n - n0;                  // block-local token idx (<= ~1008)
  for (int it = 0; it < 16; ++it) {
    unsigned k = 65u - v;                // elements e<k are row n; e>=k row n+1
    unsigned xv = x_s[nl];
    float rA = r_s[nl];
    unsigned xv2 = x_s[nl + 1u];         // nl+1 <= 1009 < 1016 always
    float rB = r_s[nl + 1u];
    unsigned idxA = xv * 65u + v;        // + e          (selected when e<k)
    unsigned idxB = xv2 * 65u - k;       // + e, u-wrap  (selected when e>=k)
    float oo[16];
#pragma unroll
    for (unsigned e = 0; e < 16u; ++e) {
      bool inA = e < k;
      unsigned idx = (inA ? idxA : idxB) + e;
      float2 p = sLP[idx];
      float rr = inA ? rA : rB;
      oo[e] = fmaf(rr, p.y, p.x);
    }
#pragma unroll
    for (int g4 = 0; g4 < 4; ++g4) {
      f32x4 q;
      q.x = oo[4 * g4 + 0];
      q.y = oo[4 * g4 + 1];
      q.z = oo[4 * g4 + 2];
      q.w = oo[4 * g4 + 3];
      *(f32x4*)(out + F + 4 * g4) = q;
    }
    // advance one sweep: +4096 floats == +63 tokens, v += 1 (4096 = 63*65+1)
    F += 4096u;
    v += 1u;
    unsigned w = (v == 65u) ? 1u : 0u;
    nl += 63u + w;
    v = w ? 0u : v;
  }
}

extern "C" void kernel_launch(void* const* d_in, const int* in_sizes, int n_in,
                              void* d_out, int out_size, void* d_ws, size_t ws_size,
                              hipStream_t stream) {
  const int* x = (const int*)d_in[0];
  const float* embed = (const float*)d_in[1];
  const float* hinit = (const float*)d_in[2];
  const float* thr = (const float*)d_in[3];
  const float* temp = (const float*)d_in[4];
  const float* ct = (const float*)d_in[5];
  const float* rt = (const float*)d_in[6];
  const float* outw = (const float*)d_in[7];
  float* ws = (float*)d_ws;
  float* out = (float*)d_out;

  hipLaunchKernelGGL(k_build, dim3(1), dim3(256), 0, stream, embed, ct, rt, hinit, outw, ws);
  // 2048 rows x 32 chunks = 65536 threads = 256 blocks
  hipLaunchKernelGGL(k_rnn_spec, dim3(256), dim3(256), 0, stream, x, ws, thr, temp, hinit);
  // 136314880 floats / 65536 per block = 2080 blocks, exact
  hipLaunchKernelGGL(k_proj, dim3(2080), dim3(256), 0, stream, x, ws, out);
}

// Round 14
// 136.115 us; speedup vs baseline: 1.5756x; 1.5756x over previous
//
#include <hip/hip_runtime.h>

// StickyRNN: B=2048, T=1024, VOCAB=65, EMBED=6, HIDDEN=7
#define TV 65
#define NB 2048
#define NT 1024

typedef float f32x4 __attribute__((ext_vector_type(4)));

// workspace layout (in floats)
#define OFF_SP 0         // SP[cur*65+prev] = float2(Stc, Src)            (2*4225)
#define OFF_LP 8450      // LP[v*65+u]      = float2(Ltc, Lrc)            (2*4225)
#define OFF_S0 16900     // S0[v] = dot(embed[v], hidden_init[0:6])       (65)
#define OFF_TC 16965     // tc[v][k]                                      (65*6)
#define OFF_RC 17355     // rc[v][k]                                      (65*6)
#define OFF_R  17792     // r[b*T+t] reset gate per step                  (2M), 64B-aligned

__global__ __launch_bounds__(128) void k_build1(
    const float* __restrict__ embed, const float* __restrict__ ct,
    const float* __restrict__ rt, const float* __restrict__ hinit,
    float* __restrict__ ws) {
  int v = threadIdx.x;
  if (v >= TV) return;
  float e[6];
#pragma unroll
  for (int k = 0; k < 6; k++) e[k] = embed[v * 6 + k];
#pragma unroll
  for (int j = 0; j < 6; j++) {
    float stc = 0.f, src = 0.f;
#pragma unroll
    for (int k = 0; k < 6; k++) {
      stc += e[k] * ct[k * 6 + j];
      src += e[k] * rt[k * 6 + j];
    }
    ws[OFF_TC + v * 6 + j] = stc;
    ws[OFF_RC + v * 6 + j] = src;
  }
  float s0 = 0.f;
#pragma unroll
  for (int k = 0; k < 6; k++) s0 += e[k] * hinit[k];
  ws[OFF_S0 + v] = s0;
}

__global__ __launch_bounds__(256) void k_build2(
    const float* __restrict__ embed, const float* __restrict__ outw,
    float* __restrict__ ws) {
  int idx = blockIdx.x * 256 + threadIdx.x;
  if (idx >= 2 * 4225) return;
  int tbl = idx / 4225;
  int e2 = idx - tbl * 4225;
  int a = e2 / 65;
  int b = e2 - a * 65;
  if (tbl == 0) {
    float stc = 0.f, src = 0.f;
#pragma unroll
    for (int k = 0; k < 6; k++) {
      stc += embed[a * 6 + k] * ws[OFF_TC + b * 6 + k];
      src += embed[a * 6 + k] * ws[OFF_RC + b * 6 + k];
    }
    ((float2*)(ws + OFF_SP))[e2] = make_float2(stc, src);
  } else {
    float ltc = 0.f, lrc = 0.f;
#pragma unroll
    for (int k = 0; k < 6; k++) {
      ltc += ws[OFF_TC + a * 6 + k] * outw[k * 65 + b];
      lrc += ws[OFF_RC + a * 6 + k] * outw[k * 65 + b];
    }
    ((float2*)(ws + OFF_LP))[e2] = make_float2(ltc, lrc);
  }
}

// Speculative chunk-parallel recurrence (bitwise-verified R2 vs R3; verbatim R8).
__global__ __launch_bounds__(256) void k_rnn_spec(
    const int* __restrict__ x, float* __restrict__ ws,
    const float* __restrict__ thr, const float* __restrict__ temp,
    const float* __restrict__ hinit) {
  __shared__ float2 sSP[4225];
  const float2* __restrict__ gSP = (const float2*)(ws + OFF_SP);
  for (int i = threadIdx.x; i < 4225; i += 256) sSP[i] = gSP[i];
  __syncthreads();

  const int tid = blockIdx.x * 256 + threadIdx.x;  // 0..65535
  const int c = tid >> 11;                         // chunk 0..31 (block-uniform)
  const int row = tid & 2047;
  const int t0 = c * 32;
  int s0 = t0 - 96;
  if (s0 < 0) s0 = 0;
  const bool exact = (s0 == 0);
  const int NG = (t0 + 32 - s0) >> 2;  // 8/16/24/32 groups of 4 steps

  const float t0v = thr[0];
  const float thr2 = t0v * t0v;
  const float invtemp = 1.0f / temp[0];
  const int* xp = x + row * NT;
  float* rbase = ws + OFF_R + row * NT;

  int4 xa = *(const int4*)(xp + s0);
  int4 xb = *(const int4*)(xp + s0 + 4);
  int4 xc = *(const int4*)(xp + s0 + 8);
  int4 xd = *(const int4*)(xp + s0 + 12);

  float pa, r_prev, omr_prev;
  float2 sp0;
  if (exact) {
    float s0v = ws[OFF_S0 + xa.x];
    sp0 = make_float2(s0v, s0v);  // 0.5*s+0.5*s == s exactly
    pa = hinit[6];
    r_prev = 0.5f;
    omr_prev = 0.5f;
  } else {
    int vm1 = xp[s0 - 1];
    sp0 = sSP[xa.x * 65 + vm1];
    pa = 0.0f;
    r_prev = 1.0f;
    omr_prev = 0.0f;
  }
  float2 sp1 = sSP[xa.y * 65 + xa.x];
  float2 sp2 = sSP[xa.z * 65 + xa.y];
  float2 sp3 = sSP[xa.w * 65 + xa.z];

#define STEP(SP, ROUT)                               \
  {                                                  \
    float sim = r_prev * (SP).y + omr_prev * (SP).x; \
    float prod = (1.0f + pa) * sim;                  \
    float aa = fmaxf(prod, 0.0f);                    \
    float add = aa - pa;                             \
    float na = pa + add;                             \
    float p = __expf((thr2 - na) * invtemp);         \
    float r = __builtin_amdgcn_rcpf(1.0f + p);       \
    float omr = 1.0f - r;                            \
    pa = omr * na;                                   \
    r_prev = r;                                      \
    omr_prev = omr;                                  \
    ROUT = r;                                        \
  }

  for (int g = 0; g < NG; ++g) {
    int offn = s0 + 4 * (g + 4);
    if (offn > NT - 4) offn = s0;
    int4 xe = *(const int4*)(xp + offn);
    float2 n0 = sSP[xb.x * 65 + xa.w];
    float2 n1 = sSP[xb.y * 65 + xb.x];
    float2 n2 = sSP[xb.z * 65 + xb.y];
    float2 n3 = sSP[xb.w * 65 + xb.z];

    float4 rq;
    STEP(sp0, rq.x);
    STEP(sp1, rq.y);
    STEP(sp2, rq.z);
    STEP(sp3, rq.w);
    int st = s0 + 4 * g;
    if (st >= t0) *(float4*)(rbase + st) = rq;  // block-uniform branch

    sp0 = n0; sp1 = n1; sp2 = n2; sp3 = n3;
    xa = xb; xb = xc; xc = xd; xd = xe;
  }
#undef STEP
}

// logits[n*65+v] = r_n * Lrc[x_n][v] + (1-r_n) * Ltc[x_n][v]
// R8 verbatim + #pragma unroll 8 (8x deeper store ILP per wave).
#define NF4 34078720u   // 2048*1024*65/4
#define PSTRIDE 524288u // 2048*256
__global__ __launch_bounds__(256) void k_proj(
    const int* __restrict__ x, const float* __restrict__ ws,
    float* __restrict__ out) {
  __shared__ float2 sLP[4225];
  const float2* __restrict__ gLP = (const float2*)(ws + OFF_LP);
  for (int i = threadIdx.x; i < 4225; i += 256) sLP[i] = gLP[i];
  __syncthreads();

  unsigned gid = blockIdx.x * 256u + threadIdx.x;
#pragma unroll 8
  for (unsigned i4 = gid; i4 < NF4; i4 += PSTRIDE) {
    unsigned base = i4 * 4u;
    unsigned n = base / 65u;
    unsigned v = base - n * 65u;  // 0..64
    unsigned n1 = n + 1u;
    if (n1 > 2097151u) n1 = 2097151u;  // last float4 has v==61: never wraps
    int xv = x[n];
    int xv2 = x[n1];
    float r = ws[OFF_R + n];
    float r2 = ws[OFF_R + n1];
    float omr = 1.0f - r;
    float omr2 = 1.0f - r2;
    unsigned offA = (unsigned)xv * 65u + v;         // element j (no wrap): offA + j
    unsigned offB = (unsigned)xv2 * 65u + v - 65u;  // element j (wrap):    offB + j
    f32x4 o;
#pragma unroll
    for (int j = 0; j < 4; ++j) {
      bool wrap = (v + (unsigned)j) >= 65u;
      unsigned off = (wrap ? offB : offA) + (unsigned)j;
      float2 p = sLP[off];
      float rr = wrap ? r2 : r;
      float oo = wrap ? omr2 : omr;
      o[j] = rr * p.y + oo * p.x;
    }
    __builtin_nontemporal_store(o, (f32x4*)(out + base));
  }
}

extern "C" void kernel_launch(void* const* d_in, const int* in_sizes, int n_in,
                              void* d_out, int out_size, void* d_ws, size_t ws_size,
                              hipStream_t stream) {
  const int* x = (const int*)d_in[0];
  const float* embed = (const float*)d_in[1];
  const float* hinit = (const float*)d_in[2];
  const float* thr = (const float*)d_in[3];
  const float* temp = (const float*)d_in[4];
  const float* ct = (const float*)d_in[5];
  const float* rt = (const float*)d_in[6];
  const float* outw = (const float*)d_in[7];
  float* ws = (float*)d_ws;
  float* out = (float*)d_out;

  hipLaunchKernelGGL(k_build1, dim3(1), dim3(128), 0, stream, embed, ct, rt, hinit, ws);
  hipLaunchKernelGGL(k_build2, dim3((2 * 4225 + 255) / 256), dim3(256), 0, stream,
                     embed, outw, ws);
  hipLaunchKernelGGL(k_rnn_spec, dim3(256), dim3(256), 0, stream, x, ws, thr, temp, hinit);
  hipLaunchKernelGGL(k_proj, dim3(2048), dim3(256), 0, stream, x, ws, out);
}